// Round 28
// baseline (295.767 us; speedup 1.0000x reference)
//
#include <hip/hip_runtime.h>

#define N_NODES 100000
#define N_EDGES 1600000
#define NBIN    98            // ceil(N / 1024); bin = dst >> 10
#define BINCAP  18432         // per-bin capacity (mean 16327, +16 sigma)
#define CHUNK   4096          // edges per binning block

typedef __attribute__((ext_vector_type(8))) _Float16 half8_t;
typedef __attribute__((ext_vector_type(4))) float f32x4_t;
typedef __attribute__((ext_vector_type(4))) _Float16 half4_t;
typedef __attribute__((ext_vector_type(2))) _Float16 half2_t;

// nt load of an int2-sized record via long long (int2 = {lo32, hi32})
static __device__ __forceinline__ int2 nt_load_i2(const int2* p) {
    long long raw = __builtin_nontemporal_load((const long long*)p);
    return make_int2((int)(unsigned)(raw & 0xffffffffll), (int)(raw >> 32));
}

// ---------------- gcur init: segment bases ----------------
__global__ void gcur_init_kernel(int* __restrict__ gcur) {
    int b = threadIdx.x;
    if (b < NBIN) gcur[b] = b * BINCAP;
}

// ---------------- LDS-staged binning, cooperative coalesced flush ----------
__global__ __launch_bounds__(256) void binning_kernel(
        const int* __restrict__ src, const int* __restrict__ dst,
        int* __restrict__ gcur, int2* __restrict__ tmp, int E) {
    __shared__ int lh[NBIN];            // histogram, then fill counters
    __shared__ int lbase[NBIN];
    __shared__ int gbase[NBIN];
    __shared__ int sc[128];
    __shared__ int2 stage[CHUNK];       // 32 KB
    __shared__ unsigned char binid[CHUNK];
    int t = threadIdx.x;
    int base = blockIdx.x * CHUNK;
    int end = base + CHUNK; if (end > E) end = E;

    for (int i = t; i < NBIN; i += 256) lh[i] = 0;
    __syncthreads();
    for (int i = base + t; i < end; i += 256)
        atomicAdd(&lh[__builtin_nontemporal_load(&dst[i]) >> 10], 1);
    __syncthreads();
    if (t < 128) sc[t] = (t < NBIN) ? lh[t] : 0;
    __syncthreads();
    for (int off = 1; off < 128; off <<= 1) {
        int x = 0;
        if (t < 128 && t >= off) x = sc[t - off];
        __syncthreads();
        if (t < 128) sc[t] += x;
        __syncthreads();
    }
    if (t < NBIN) {
        int cnt = lh[t];
        lbase[t] = sc[t] - cnt;
        gbase[t] = cnt ? atomicAdd(&gcur[t], cnt) : 0;
        lh[t] = 0;                      // reuse as fill cursor
    }
    __syncthreads();
    for (int i = base + t; i < end; i += 256) {
        int s = __builtin_nontemporal_load(&src[i]);
        int d = __builtin_nontemporal_load(&dst[i]);
        int b = d >> 10;
        int lp = lbase[b] + atomicAdd(&lh[b], 1);
        stage[lp] = make_int2(s, d);
        binid[lp] = (unsigned char)b;
    }
    __syncthreads();
    int tot = end - base;
    for (int i = t; i < tot; i += 256) {  // consecutive threads -> consecutive
        int b = binid[i];                  // global addrs within a segment
        tmp[gbase[b] + (i - lbase[b])] = stage[i];
    }
}

// ---------------- bdeg: 4 sub-blocks per bin, LDS counts + global agg ----------
__global__ __launch_bounds__(1024) void bdeg_kernel(const int* __restrict__ gcur,
                                                    const int2* __restrict__ tmp,
                                                    int* __restrict__ deg, int n) {
    __shared__ int lc[1024];
    int b = blockIdx.x >> 2, q = blockIdx.x & 3, t = threadIdx.x;
    lc[t] = 0;
    __syncthreads();
    int e0 = b * BINCAP, cnt = gcur[b] - e0;
    int q0 = e0 + (cnt * q) / 4, q1 = e0 + (cnt * (q + 1)) / 4;
    for (int e = q0 + t; e < q1; e += 1024) {
        int2 p = nt_load_i2(&tmp[e]);
        atomicAdd(&lc[p.y & 1023], 1);
    }
    __syncthreads();
    int node = b * 1024 + t;
    if (lc[t] && node < n) atomicAdd(&deg[node], lc[t]);
}

// ---------------- place: 4 sub-blocks per bin; slot ranges reserved via cur ----
__global__ __launch_bounds__(1024) void place_kernel(const int* __restrict__ gcur,
                                                     const int2* __restrict__ tmp,
                                                     const int* __restrict__ rowptr,
                                                     int* __restrict__ cur,
                                                     const float* __restrict__ dinv,
                                                     int2* __restrict__ csr, int n) {
    __shared__ int lc[1024];
    __shared__ int gb[1024];
    int b = blockIdx.x >> 2, q = blockIdx.x & 3, t = threadIdx.x;
    lc[t] = 0;
    __syncthreads();
    int e0 = b * BINCAP, cnt = gcur[b] - e0;
    int q0 = e0 + (cnt * q) / 4, q1 = e0 + (cnt * (q + 1)) / 4;
    for (int e = q0 + t; e < q1; e += 1024) {
        int2 p = nt_load_i2(&tmp[e]);
        atomicAdd(&lc[p.y & 1023], 1);
    }
    __syncthreads();
    gb[t] = lc[t] ? atomicAdd(&cur[b * 1024 + t], lc[t]) : 0;
    lc[t] = 0;
    __syncthreads();
    for (int e = q0 + t; e < q1; e += 1024) {
        int2 p = nt_load_i2(&tmp[e]);
        int sl = p.y & 1023;
        int pos = gb[sl] + atomicAdd(&lc[sl], 1);
        float w = dinv[p.x] * dinv[p.y];
        csr[rowptr[p.y] + pos] = make_int2(p.x, __float_as_int(w));
    }
}

// ---------------- scan pass 1 + fused dinv ----------------
__global__ void scan_sums_kernel(const int* __restrict__ deg, int* __restrict__ bsums,
                                 float* __restrict__ dinv, int n) {
    __shared__ int sd[256];
    int t = threadIdx.x;
    int base = blockIdx.x * 1024 + t * 4;
    int s = 0;
    #pragma unroll
    for (int j = 0; j < 4; ++j) {
        int i = base + j;
        if (i < n) {
            int d = deg[i];
            s += d;
            dinv[i] = rsqrtf((float)(d + 1));   // +1 = self-loop
        }
    }
    sd[t] = s; __syncthreads();
    for (int off = 128; off > 0; off >>= 1) {
        if (t < off) sd[t] += sd[t + off];
        __syncthreads();
    }
    if (t == 0) bsums[blockIdx.x] = sd[0];
}

__global__ void scan_offsets_kernel(int* __restrict__ bsums, int nb, int* __restrict__ rowptr_tail) {
    __shared__ int sd[128];
    int t = threadIdx.x;
    int v = (t < nb) ? bsums[t] : 0;
    sd[t] = v; __syncthreads();
    for (int off = 1; off < 128; off <<= 1) {
        int x = (t >= off) ? sd[t - off] : 0;
        __syncthreads();
        sd[t] += x;
        __syncthreads();
    }
    if (t < nb) bsums[t] = sd[t] - v;      // exclusive
    if (t == 0) *rowptr_tail = N_EDGES;    // rowptr[n]
}

__global__ void scan_final_kernel(const int* __restrict__ deg, const int* __restrict__ bsums,
                                  int* __restrict__ rowptr, int n) {
    __shared__ int sd[256];
    int t = threadIdx.x;
    int base = blockIdx.x * 1024 + t * 4;
    int v[4], pre[4], s = 0;
    #pragma unroll
    for (int j = 0; j < 4; ++j) {
        int i = base + j;
        v[j] = (i < n) ? deg[i] : 0;
        pre[j] = s; s += v[j];
    }
    sd[t] = s;
    int mine = s;
    __syncthreads();
    for (int off = 1; off < 256; off <<= 1) {
        int x = (t >= off) ? sd[t - off] : 0;
        __syncthreads();
        sd[t] += x;
        __syncthreads();
    }
    int excl = sd[t] - mine + bsums[blockIdx.x];
    #pragma unroll
    for (int j = 0; j < 4; ++j) {
        int i = base + j;
        if (i < n) rowptr[i] = excl + pre[j];
    }
}

// ---------------- x -> fp16 plane ----------------
__global__ void x16_kernel(const float* __restrict__ x, _Float16* __restrict__ y, int total4) {
    int i = blockIdx.x * blockDim.x + threadIdx.x;
    if (i >= total4) return;
    float4 v = *(const float4*)&x[(size_t)i * 4];
    half4_t o;
    o[0] = (_Float16)v.x; o[1] = (_Float16)v.y;
    o[2] = (_Float16)v.z; o[3] = (_Float16)v.w;
    *(half4_t*)&y[(size_t)i * 4] = o;
}

// ---------------- W2fc = W2 @ Wfc -> transposed fp16 [48][256]; bfc2 = b2@Wfc+bfc --
__global__ __launch_bounds__(256) void w2fc_kernel(
        const float* __restrict__ W2, const float* __restrict__ Wfc,
        const float* __restrict__ b2, const float* __restrict__ bfc,
        _Float16* __restrict__ T16, float* __restrict__ bfc2) {
    __shared__ float wf[64 * 40];
    int t = threadIdx.x;
    for (int i = t; i < 64 * 40; i += 256) wf[i] = Wfc[i];
    __syncthreads();
    float acc[40];
    #pragma unroll
    for (int c = 0; c < 40; ++c) acc[c] = 0.f;
    for (int k = 0; k < 64; ++k) {
        float a = W2[t * 64 + k];
        #pragma unroll
        for (int c = 0; c < 40; ++c) acc[c] += a * wf[k * 40 + c];
    }
    #pragma unroll
    for (int c = 0; c < 40; ++c) T16[c * 256 + t] = (_Float16)acc[c];
    #pragma unroll
    for (int r = 40; r < 48; ++r) T16[r * 256 + t] = (_Float16)0.f;
    if (t < 40) {
        float s = bfc[t];
        for (int k = 0; k < 64; ++k) s += b2[k] * wf[k * 40 + t];
        bfc2[t] = s;
    }
}

// ---------------- W1 [128][256] -> W1t fp16 [256][128] ----------------
__global__ void w1t_kernel(const float* __restrict__ W1, _Float16* __restrict__ t16) {
    int k = blockIdx.x;          // 0..127
    int n = threadIdx.x;         // 0..255
    t16[n * 128 + k] = (_Float16)W1[k * 256 + n];
}

// ---------------- gather1: 2 nodes per wave (32 lanes x half4 = 256B row) --------
__global__ void gather1_kernel(const int* __restrict__ rowptr, const int2* __restrict__ csr,
                               const float* __restrict__ dinv, const _Float16* __restrict__ x,
                               _Float16* __restrict__ o16, int n) {
    const int lane = threadIdx.x & 63;
    const int h = lane >> 5;          // node sub-group 0/1
    const int c = lane & 31;          // owns cols c*4..c*4+3
    const int wid0 = (blockIdx.x * blockDim.x + threadIdx.x) >> 6;
    const int nwav = (gridDim.x * blockDim.x) >> 6;
    for (int base = wid0 * 2; base < n; base += nwav * 2) {
        int node = base + h;
        bool active = node < n;
        int nd = active ? node : 0;
        float di = dinv[nd];
        float selfw = di * di;
        int e0 = active ? rowptr[nd] : 0;
        int e1 = active ? rowptr[nd + 1] : 0;
        half4_t sv = *(const half4_t*)&x[(size_t)nd * 128 + c * 4];
        float a[4];
        #pragma unroll
        for (int j = 0; j < 4; ++j) a[j] = (float)sv[j] * selfw;
        int e = e0;
        for (; e + 8 <= e1; e += 8) {
            int2 p[8]; half4_t v[8];
            #pragma unroll
            for (int u = 0; u < 8; ++u) p[u] = nt_load_i2(&csr[e + u]);
            #pragma unroll
            for (int u = 0; u < 8; ++u)
                v[u] = *(const half4_t*)&x[(size_t)p[u].x * 128 + c * 4];
            #pragma unroll
            for (int u = 0; u < 8; ++u) {
                float w = __int_as_float(p[u].y);
                #pragma unroll
                for (int j = 0; j < 4; ++j) a[j] += (float)v[u][j] * w;
            }
        }
        for (; e < e1; ++e) {
            int2 p = nt_load_i2(&csr[e]);
            float w = __int_as_float(p.y);
            half4_t v = *(const half4_t*)&x[(size_t)p.x * 128 + c * 4];
            #pragma unroll
            for (int j = 0; j < 4; ++j) a[j] += (float)v[j] * w;
        }
        if (active) {
            half4_t ov;
            #pragma unroll
            for (int j = 0; j < 4; ++j) ov[j] = (_Float16)a[j];
            *(half4_t*)&o16[(size_t)node * 128 + c * 4] = ov;
        }
    }
}

// ---------------- gather2: 12 nodes per wave (5 lanes x half8 = 80B row) ---------
__global__ void gather2_kernel(const int* __restrict__ rowptr, const int2* __restrict__ csr,
                               const float* __restrict__ dinv, const _Float16* __restrict__ xw,
                               const float* __restrict__ bias, float* __restrict__ out, int n) {
    const int lane = threadIdx.x & 63;
    const int g = lane / 5;           // 0..12 (12 => inactive)
    const int c = lane - g * 5;       // 0..4; owns cols c*8..c*8+7
    const int wid0 = (blockIdx.x * blockDim.x + threadIdx.x) >> 6;
    const int nwav = (gridDim.x * blockDim.x) >> 6;
    for (int base = wid0 * 12; base < n; base += nwav * 12) {
        int node = base + g;
        bool active = (g < 12) && (node < n);
        int nd = active ? node : 0;
        float di = dinv[nd];
        float selfw = di * di;
        int e0 = active ? rowptr[nd] : 0;
        int e1 = active ? rowptr[nd + 1] : 0;
        half8_t sv = *(const half8_t*)&xw[(size_t)nd * 40 + c * 8];
        float acc[8];
        #pragma unroll
        for (int j = 0; j < 8; ++j) acc[j] = (float)sv[j] * selfw;
        int e = e0;
        for (; e + 4 <= e1; e += 4) {
            int2 p[4]; half8_t v[4];
            #pragma unroll
            for (int u = 0; u < 4; ++u) p[u] = nt_load_i2(&csr[e + u]);
            #pragma unroll
            for (int u = 0; u < 4; ++u)
                v[u] = *(const half8_t*)&xw[(size_t)p[u].x * 40 + c * 8];
            #pragma unroll
            for (int u = 0; u < 4; ++u) {
                float w = __int_as_float(p[u].y);
                #pragma unroll
                for (int j = 0; j < 8; ++j) acc[j] += (float)v[u][j] * w;
            }
        }
        for (; e < e1; ++e) {
            int2 p = nt_load_i2(&csr[e]);
            float w = __int_as_float(p.y);
            half8_t v = *(const half8_t*)&xw[(size_t)p.x * 40 + c * 8];
            #pragma unroll
            for (int j = 0; j < 8; ++j) acc[j] += (float)v[j] * w;
        }
        if (active) {
            #pragma unroll
            for (int j = 0; j < 8; ++j) acc[j] += bias[c * 8 + j];
            *(float4*)&out[(size_t)node * 40 + c * 8] =
                make_float4(acc[0], acc[1], acc[2], acc[3]);
            *(float4*)&out[(size_t)node * 40 + c * 8 + 4] =
                make_float4(acc[4], acc[5], acc[6], acc[7]);
        }
    }
}

// ---------------- gemm1: fp16 MFMA, LDS-staged, BK=64 (2 K-tiles) ----------------
__global__ __launch_bounds__(256) void gemm1_mfma(
        const _Float16* __restrict__ A16, const _Float16* __restrict__ B16,
        const float* __restrict__ bias, _Float16* __restrict__ C16, int M) {
    constexpr int K = 128, N = 256, LDK = 72;   // pad 64->72: 2-way banks
    __shared__ _Float16 sA[128 * LDK];
    __shared__ _Float16 sB[128 * LDK];
    const int t = threadIdx.x;
    const int m0 = blockIdx.x * 128, n0 = blockIdx.y * 128;
    const int wave = t >> 6, lane = t & 63;
    const int wm = wave >> 1, wn = wave & 1;
    const int l15 = lane & 15, k8 = (lane >> 4) * 8;

    f32x4_t acc[4][4] = {};

    for (int k0 = 0; k0 < K; k0 += 64) {
        #pragma unroll
        for (int u = 0; u < 4; ++u) {
            int idx = t + u * 256;               // 0..1023 -> 128 rows x 8 chunks
            int r = idx >> 3, c = (idx & 7) * 8;
            int gr = m0 + r; if (gr > M - 1) gr = M - 1;
            *(uint4*)&sA[r * LDK + c] = *(const uint4*)&A16[(size_t)gr * K + k0 + c];
            int bn = n0 + r;
            *(uint4*)&sB[r * LDK + c] = *(const uint4*)&B16[(size_t)bn * K + k0 + c];
        }
        __syncthreads();
        #pragma unroll
        for (int ks = 0; ks < 2; ++ks) {         // two K=32 sub-steps per tile
            const int ko = ks * 32 + k8;
            half8_t fa[4], fb[4];
            #pragma unroll
            for (int i = 0; i < 4; ++i) {
                int m = wm * 64 + i * 16 + l15;
                fa[i] = *(const half8_t*)&sA[m * LDK + ko];
                int nn = wn * 64 + i * 16 + l15;
                fb[i] = *(const half8_t*)&sB[nn * LDK + ko];
            }
            #pragma unroll
            for (int i = 0; i < 4; ++i)
                #pragma unroll
                for (int j = 0; j < 4; ++j)
                    acc[i][j] = __builtin_amdgcn_mfma_f32_16x16x32_f16(fa[i], fb[j], acc[i][j], 0, 0, 0);
        }
        __syncthreads();
    }

    const int r4 = (lane >> 4) * 4;
    #pragma unroll
    for (int j = 0; j < 4; ++j) {
        int col = n0 + wn * 64 + j * 16 + l15;
        float bv = bias[col];
        #pragma unroll
        for (int i = 0; i < 4; ++i) {
            #pragma unroll
            for (int r = 0; r < 4; ++r) {
                int row = m0 + wm * 64 + i * 16 + r4 + r;
                if (row < M) {
                    float v = fmaxf(acc[i][j][r] + bv, 0.f);
                    C16[(size_t)row * N + col] = (_Float16)v;
                }
            }
        }
    }
}

// ---------------- gemm2: fp16 MFMA, LDS-staged; fp16 output ----------------
__global__ __launch_bounds__(256) void gemm2_mfma(
        const _Float16* __restrict__ A16, const _Float16* __restrict__ B16,
        _Float16* __restrict__ C16, int M) {
    constexpr int K = 256, LDK = 40;
    __shared__ _Float16 sA[128 * LDK];
    __shared__ _Float16 sB[48 * LDK];
    const int t = threadIdx.x;
    const int m0 = blockIdx.x * 128;
    const int wave = t >> 6, lane = t & 63;
    const int l15 = lane & 15, k8 = (lane >> 4) * 8;

    f32x4_t acc[2][3] = {};

    for (int k0 = 0; k0 < K; k0 += 32) {
        #pragma unroll
        for (int u = 0; u < 2; ++u) {
            int idx = t + u * 256;
            int r = idx >> 2, c = (idx & 3) * 8;
            int gr = m0 + r; if (gr > M - 1) gr = M - 1;
            *(uint4*)&sA[r * LDK + c] = *(const uint4*)&A16[(size_t)gr * K + k0 + c];
        }
        if (t < 192) {
            int r = t >> 2, c = (t & 3) * 8;
            *(uint4*)&sB[r * LDK + c] = *(const uint4*)&B16[(size_t)r * K + k0 + c];
        }
        __syncthreads();
        half8_t fa[2], fb[3];
        #pragma unroll
        for (int i = 0; i < 2; ++i) {
            int m = wave * 32 + i * 16 + l15;
            fa[i] = *(const half8_t*)&sA[m * LDK + k8];
        }
        #pragma unroll
        for (int j = 0; j < 3; ++j) {
            int nn = j * 16 + l15;
            fb[j] = *(const half8_t*)&sB[nn * LDK + k8];
        }
        #pragma unroll
        for (int i = 0; i < 2; ++i)
            #pragma unroll
            for (int j = 0; j < 3; ++j)
                acc[i][j] = __builtin_amdgcn_mfma_f32_16x16x32_f16(fa[i], fb[j], acc[i][j], 0, 0, 0);
        __syncthreads();
    }

    const int r4 = (lane >> 4) * 4;
    #pragma unroll
    for (int i = 0; i < 2; ++i)
        #pragma unroll
        for (int j = 0; j < 3; ++j) {
            int col = j * 16 + l15;
            if (col < 40) {
                #pragma unroll
                for (int r = 0; r < 4; ++r) {
                    int row = m0 + wave * 32 + i * 16 + r4 + r;
                    if (row < M) C16[(size_t)row * 40 + col] = (_Float16)acc[i][j][r];
                }
            }
        }
}

extern "C" void kernel_launch(void* const* d_in, const int* in_sizes, int n_in,
                              void* d_out, int out_size, void* d_ws, size_t ws_size,
                              hipStream_t stream) {
    const float* x   = (const float*)d_in[0];
    const int*   ei  = (const int*)d_in[1];
    const float* W1  = (const float*)d_in[2];
    const float* b1  = (const float*)d_in[3];
    const float* W2  = (const float*)d_in[4];
    const float* b2  = (const float*)d_in[5];
    const float* Wfc = (const float*)d_in[6];
    const float* bfc = (const float*)d_in[7];
    float* out = (float*)d_out;

    const int n = N_NODES, E = N_EDGES;
    const int* src = ei;
    const int* dst = ei + E;

    char* ws = (char*)d_ws;
    int*       deg    = (int*)(ws + 0);            // 400 KB
    float*     dinv   = (float*)(ws + 409600);     // 400 KB
    int*       rowptr = (int*)(ws + 819200);       // ~400 KB
    int*       bsums  = (int*)(ws + 1219584);      // 512 B
    float*     bfc2   = (float*)(ws + 1220096);    // 512 B
    _Float16*  w2t16  = (_Float16*)(ws + 1220608); // 24 KB [48][256]
    _Float16*  w1t16  = (_Float16*)(ws + 1245184); // 64 KB [256][128]
    int*       gcur   = (int*)(ws + 1310720);      // 512 B
    int*       cur    = (int*)(ws + 1311232);      // 401,408 B (98*1024 ints)
    int2*      csr    = (int2*)(ws + 1712640);     // 12.8 MB
    int2*      tmp    = (int2*)(ws + 14512640);    // 14.45 MB (capacity-padded bins)
    _Float16*  x16    = (_Float16*)(ws + 28963328);  // 25.6 MB
    _Float16*  aggx16 = (_Float16*)(ws + 54563328);  // 25.6 MB
    _Float16*  h116   = (_Float16*)(ws + 80163328);  // 51.2 MB
    _Float16*  h1w16  = (_Float16*)(ws + 131363328); // 8 MB ([100k][40] fp16)

    const int nb = (n + 1023) / 1024;             // 98 scan blocks
    const int nchunk = (E + CHUNK - 1) / CHUNK;   // 391 binning blocks

    // ---- CSR build: self-reserving binning -> sub-block deg/place ----
    gcur_init_kernel<<<1, 128, 0, stream>>>(gcur);
    hipMemsetAsync(deg, 0, (size_t)n * sizeof(int), stream);
    hipMemsetAsync(cur, 0, (size_t)NBIN * 1024 * sizeof(int), stream);
    binning_kernel<<<nchunk, 256, 0, stream>>>(src, dst, gcur, tmp, E);
    bdeg_kernel<<<NBIN * 4, 1024, 0, stream>>>(gcur, tmp, deg, n);
    scan_sums_kernel<<<nb, 256, 0, stream>>>(deg, bsums, dinv, n);
    scan_offsets_kernel<<<1, 128, 0, stream>>>(bsums, nb, rowptr + n);
    scan_final_kernel<<<nb, 256, 0, stream>>>(deg, bsums, rowptr, n);
    place_kernel<<<NBIN * 4, 1024, 0, stream>>>(gcur, tmp, rowptr, cur, dinv, csr, n);

    // ---- weight precomputes + x fp16 plane ----
    w2fc_kernel<<<1, 256, 0, stream>>>(W2, Wfc, b2, bfc, w2t16, bfc2);
    w1t_kernel<<<128, 256, 0, stream>>>(W1, w1t16);
    x16_kernel<<<(n * 128 / 4 + 255) / 256, 256, 0, stream>>>(x, x16, n * 32);

    // ---- layer 1: aggx(fp16) = A_hat @ x16; h1(fp16) = relu(aggx @ W1 + b1) ----
    gather1_kernel<<<2048, 256, 0, stream>>>(rowptr, csr, dinv, x16, aggx16, n);
    gemm1_mfma<<<dim3((n + 127) / 128, 2), 256, 0, stream>>>(
        aggx16, w1t16, b1, h116, n);

    // ---- layer 2 + FC folded: out = A_hat @ (h1 @ W2fc) + bfc2 ----
    gemm2_mfma<<<(n + 127) / 128, 256, 0, stream>>>(h116, w2t16, h1w16, n);
    gather2_kernel<<<2048, 256, 0, stream>>>(rowptr, csr, dinv, h1w16, bfc2, out, n);
}

// Round 29
// 283.888 us; speedup vs baseline: 1.0418x; 1.0418x over previous
//
#include <hip/hip_runtime.h>

#define N_NODES 100000
#define N_EDGES 1600000
#define NBIN    98            // ceil(N / 1024); bin = dst >> 10
#define BINCAP  18432         // per-bin capacity (mean 16327, +16 sigma)
#define CHUNK   4096          // edges per binning block

typedef __attribute__((ext_vector_type(8))) _Float16 half8_t;
typedef __attribute__((ext_vector_type(4))) float f32x4_t;
typedef __attribute__((ext_vector_type(4))) _Float16 half4_t;
typedef __attribute__((ext_vector_type(2))) _Float16 half2_t;

// nt load of an int2-sized record via long long (int2 = {lo32, hi32})
static __device__ __forceinline__ int2 nt_load_i2(const int2* p) {
    long long raw = __builtin_nontemporal_load((const long long*)p);
    return make_int2((int)(unsigned)(raw & 0xffffffffll), (int)(raw >> 32));
}

// ---------------- gcur init: segment bases ----------------
__global__ void gcur_init_kernel(int* __restrict__ gcur) {
    int b = threadIdx.x;
    if (b < NBIN) gcur[b] = b * BINCAP;
}

// ---------------- LDS-staged binning, cooperative coalesced flush ----------
__global__ __launch_bounds__(256) void binning_kernel(
        const int* __restrict__ src, const int* __restrict__ dst,
        int* __restrict__ gcur, int2* __restrict__ tmp, int E) {
    __shared__ int lh[NBIN];            // histogram, then fill counters
    __shared__ int lbase[NBIN];
    __shared__ int gbase[NBIN];
    __shared__ int sc[128];
    __shared__ int2 stage[CHUNK];       // 32 KB
    __shared__ unsigned char binid[CHUNK];
    int t = threadIdx.x;
    int base = blockIdx.x * CHUNK;
    int end = base + CHUNK; if (end > E) end = E;

    for (int i = t; i < NBIN; i += 256) lh[i] = 0;
    __syncthreads();
    for (int i = base + t; i < end; i += 256)
        atomicAdd(&lh[__builtin_nontemporal_load(&dst[i]) >> 10], 1);
    __syncthreads();
    if (t < 128) sc[t] = (t < NBIN) ? lh[t] : 0;
    __syncthreads();
    for (int off = 1; off < 128; off <<= 1) {
        int x = 0;
        if (t < 128 && t >= off) x = sc[t - off];
        __syncthreads();
        if (t < 128) sc[t] += x;
        __syncthreads();
    }
    if (t < NBIN) {
        int cnt = lh[t];
        lbase[t] = sc[t] - cnt;
        gbase[t] = cnt ? atomicAdd(&gcur[t], cnt) : 0;
        lh[t] = 0;                      // reuse as fill cursor
    }
    __syncthreads();
    for (int i = base + t; i < end; i += 256) {
        int s = __builtin_nontemporal_load(&src[i]);
        int d = __builtin_nontemporal_load(&dst[i]);
        int b = d >> 10;
        int lp = lbase[b] + atomicAdd(&lh[b], 1);
        stage[lp] = make_int2(s, d);
        binid[lp] = (unsigned char)b;
    }
    __syncthreads();
    int tot = end - base;
    for (int i = t; i < tot; i += 256) {  // consecutive threads -> consecutive
        int b = binid[i];                  // global addrs within a segment
        tmp[gbase[b] + (i - lbase[b])] = stage[i];
    }
}

// ---------------- bdeg: 4 sub-blocks per bin, LDS counts + global agg ----------
__global__ __launch_bounds__(1024) void bdeg_kernel(const int* __restrict__ gcur,
                                                    const int2* __restrict__ tmp,
                                                    int* __restrict__ deg, int n) {
    __shared__ int lc[1024];
    int b = blockIdx.x >> 2, q = blockIdx.x & 3, t = threadIdx.x;
    lc[t] = 0;
    __syncthreads();
    int e0 = b * BINCAP, cnt = gcur[b] - e0;
    int q0 = e0 + (cnt * q) / 4, q1 = e0 + (cnt * (q + 1)) / 4;
    for (int e = q0 + t; e < q1; e += 1024) {
        int2 p = nt_load_i2(&tmp[e]);
        atomicAdd(&lc[p.y & 1023], 1);
    }
    __syncthreads();
    int node = b * 1024 + t;
    if (lc[t] && node < n) atomicAdd(&deg[node], lc[t]);
}

// ---------------- place: 4 sub-blocks per bin; slot ranges reserved via cur ----
__global__ __launch_bounds__(1024) void place_kernel(const int* __restrict__ gcur,
                                                     const int2* __restrict__ tmp,
                                                     const int* __restrict__ rowptr,
                                                     int* __restrict__ cur,
                                                     const float* __restrict__ dinv,
                                                     int2* __restrict__ csr, int n) {
    __shared__ int lc[1024];
    __shared__ int gb[1024];
    int b = blockIdx.x >> 2, q = blockIdx.x & 3, t = threadIdx.x;
    lc[t] = 0;
    __syncthreads();
    int e0 = b * BINCAP, cnt = gcur[b] - e0;
    int q0 = e0 + (cnt * q) / 4, q1 = e0 + (cnt * (q + 1)) / 4;
    for (int e = q0 + t; e < q1; e += 1024) {
        int2 p = nt_load_i2(&tmp[e]);
        atomicAdd(&lc[p.y & 1023], 1);
    }
    __syncthreads();
    gb[t] = lc[t] ? atomicAdd(&cur[b * 1024 + t], lc[t]) : 0;
    lc[t] = 0;
    __syncthreads();
    for (int e = q0 + t; e < q1; e += 1024) {
        int2 p = nt_load_i2(&tmp[e]);
        int sl = p.y & 1023;
        int pos = gb[sl] + atomicAdd(&lc[sl], 1);
        float w = dinv[p.x] * dinv[p.y];
        csr[rowptr[p.y] + pos] = make_int2(p.x, __float_as_int(w));
    }
}

// ---------------- scan pass 1 + fused dinv ----------------
__global__ void scan_sums_kernel(const int* __restrict__ deg, int* __restrict__ bsums,
                                 float* __restrict__ dinv, int n) {
    __shared__ int sd[256];
    int t = threadIdx.x;
    int base = blockIdx.x * 1024 + t * 4;
    int s = 0;
    #pragma unroll
    for (int j = 0; j < 4; ++j) {
        int i = base + j;
        if (i < n) {
            int d = deg[i];
            s += d;
            dinv[i] = rsqrtf((float)(d + 1));   // +1 = self-loop
        }
    }
    sd[t] = s; __syncthreads();
    for (int off = 128; off > 0; off >>= 1) {
        if (t < off) sd[t] += sd[t + off];
        __syncthreads();
    }
    if (t == 0) bsums[blockIdx.x] = sd[0];
}

__global__ void scan_offsets_kernel(int* __restrict__ bsums, int nb, int* __restrict__ rowptr_tail) {
    __shared__ int sd[128];
    int t = threadIdx.x;
    int v = (t < nb) ? bsums[t] : 0;
    sd[t] = v; __syncthreads();
    for (int off = 1; off < 128; off <<= 1) {
        int x = (t >= off) ? sd[t - off] : 0;
        __syncthreads();
        sd[t] += x;
        __syncthreads();
    }
    if (t < nb) bsums[t] = sd[t] - v;      // exclusive
    if (t == 0) *rowptr_tail = N_EDGES;    // rowptr[n]
}

__global__ void scan_final_kernel(const int* __restrict__ deg, const int* __restrict__ bsums,
                                  int* __restrict__ rowptr, int n) {
    __shared__ int sd[256];
    int t = threadIdx.x;
    int base = blockIdx.x * 1024 + t * 4;
    int v[4], pre[4], s = 0;
    #pragma unroll
    for (int j = 0; j < 4; ++j) {
        int i = base + j;
        v[j] = (i < n) ? deg[i] : 0;
        pre[j] = s; s += v[j];
    }
    sd[t] = s;
    int mine = s;
    __syncthreads();
    for (int off = 1; off < 256; off <<= 1) {
        int x = (t >= off) ? sd[t - off] : 0;
        __syncthreads();
        sd[t] += x;
        __syncthreads();
    }
    int excl = sd[t] - mine + bsums[blockIdx.x];
    #pragma unroll
    for (int j = 0; j < 4; ++j) {
        int i = base + j;
        if (i < n) rowptr[i] = excl + pre[j];
    }
}

// ---------------- x -> fp16 plane ----------------
__global__ void x16_kernel(const float* __restrict__ x, _Float16* __restrict__ y, int total4) {
    int i = blockIdx.x * blockDim.x + threadIdx.x;
    if (i >= total4) return;
    float4 v = *(const float4*)&x[(size_t)i * 4];
    half4_t o;
    o[0] = (_Float16)v.x; o[1] = (_Float16)v.y;
    o[2] = (_Float16)v.z; o[3] = (_Float16)v.w;
    *(half4_t*)&y[(size_t)i * 4] = o;
}

// ---------------- W2fc = W2 @ Wfc -> transposed fp16 [48][256]; bfc2 = b2@Wfc+bfc --
__global__ __launch_bounds__(256) void w2fc_kernel(
        const float* __restrict__ W2, const float* __restrict__ Wfc,
        const float* __restrict__ b2, const float* __restrict__ bfc,
        _Float16* __restrict__ T16, float* __restrict__ bfc2) {
    __shared__ float wf[64 * 40];
    int t = threadIdx.x;
    for (int i = t; i < 64 * 40; i += 256) wf[i] = Wfc[i];
    __syncthreads();
    float acc[40];
    #pragma unroll
    for (int c = 0; c < 40; ++c) acc[c] = 0.f;
    for (int k = 0; k < 64; ++k) {
        float a = W2[t * 64 + k];
        #pragma unroll
        for (int c = 0; c < 40; ++c) acc[c] += a * wf[k * 40 + c];
    }
    #pragma unroll
    for (int c = 0; c < 40; ++c) T16[c * 256 + t] = (_Float16)acc[c];
    #pragma unroll
    for (int r = 40; r < 48; ++r) T16[r * 256 + t] = (_Float16)0.f;
    if (t < 40) {
        float s = bfc[t];
        for (int k = 0; k < 64; ++k) s += b2[k] * wf[k * 40 + t];
        bfc2[t] = s;
    }
}

// ---------------- W1 [128][256] -> W1t fp16 [256][128] ----------------
__global__ void w1t_kernel(const float* __restrict__ W1, _Float16* __restrict__ t16) {
    int k = blockIdx.x;          // 0..127
    int n = threadIdx.x;         // 0..255
    t16[n * 128 + k] = (_Float16)W1[k * 256 + n];
}

// ---------------- gather1: 2 nodes per wave (32 lanes x half4 = 256B row) --------
__global__ void gather1_kernel(const int* __restrict__ rowptr, const int2* __restrict__ csr,
                               const float* __restrict__ dinv, const _Float16* __restrict__ x,
                               _Float16* __restrict__ o16, int n) {
    const int lane = threadIdx.x & 63;
    const int h = lane >> 5;          // node sub-group 0/1
    const int c = lane & 31;          // owns cols c*4..c*4+3
    const int wid0 = (blockIdx.x * blockDim.x + threadIdx.x) >> 6;
    const int nwav = (gridDim.x * blockDim.x) >> 6;
    for (int base = wid0 * 2; base < n; base += nwav * 2) {
        int node = base + h;
        bool active = node < n;
        int nd = active ? node : 0;
        float di = dinv[nd];
        float selfw = di * di;
        int e0 = active ? rowptr[nd] : 0;
        int e1 = active ? rowptr[nd + 1] : 0;
        half4_t sv = *(const half4_t*)&x[(size_t)nd * 128 + c * 4];
        float a[4];
        #pragma unroll
        for (int j = 0; j < 4; ++j) a[j] = (float)sv[j] * selfw;
        int e = e0;
        for (; e + 8 <= e1; e += 8) {
            int2 p[8]; half4_t v[8];
            #pragma unroll
            for (int u = 0; u < 8; ++u) p[u] = nt_load_i2(&csr[e + u]);
            #pragma unroll
            for (int u = 0; u < 8; ++u)
                v[u] = *(const half4_t*)&x[(size_t)p[u].x * 128 + c * 4];
            #pragma unroll
            for (int u = 0; u < 8; ++u) {
                float w = __int_as_float(p[u].y);
                #pragma unroll
                for (int j = 0; j < 4; ++j) a[j] += (float)v[u][j] * w;
            }
        }
        for (; e < e1; ++e) {
            int2 p = nt_load_i2(&csr[e]);
            float w = __int_as_float(p.y);
            half4_t v = *(const half4_t*)&x[(size_t)p.x * 128 + c * 4];
            #pragma unroll
            for (int j = 0; j < 4; ++j) a[j] += (float)v[j] * w;
        }
        if (active) {
            half4_t ov;
            #pragma unroll
            for (int j = 0; j < 4; ++j) ov[j] = (_Float16)a[j];
            *(half4_t*)&o16[(size_t)node * 128 + c * 4] = ov;
        }
    }
}

// ---------------- gather2: 12 nodes per wave (5 lanes x half8 = 80B row) ---------
__global__ void gather2_kernel(const int* __restrict__ rowptr, const int2* __restrict__ csr,
                               const float* __restrict__ dinv, const _Float16* __restrict__ xw,
                               const float* __restrict__ bias, float* __restrict__ out, int n) {
    const int lane = threadIdx.x & 63;
    const int g = lane / 5;           // 0..12 (12 => inactive)
    const int c = lane - g * 5;       // 0..4; owns cols c*8..c*8+7
    const int wid0 = (blockIdx.x * blockDim.x + threadIdx.x) >> 6;
    const int nwav = (gridDim.x * blockDim.x) >> 6;
    for (int base = wid0 * 12; base < n; base += nwav * 12) {
        int node = base + g;
        bool active = (g < 12) && (node < n);
        int nd = active ? node : 0;
        float di = dinv[nd];
        float selfw = di * di;
        int e0 = active ? rowptr[nd] : 0;
        int e1 = active ? rowptr[nd + 1] : 0;
        half8_t sv = *(const half8_t*)&xw[(size_t)nd * 40 + c * 8];
        float acc[8];
        #pragma unroll
        for (int j = 0; j < 8; ++j) acc[j] = (float)sv[j] * selfw;
        int e = e0;
        for (; e + 4 <= e1; e += 4) {
            int2 p[4]; half8_t v[4];
            #pragma unroll
            for (int u = 0; u < 4; ++u) p[u] = nt_load_i2(&csr[e + u]);
            #pragma unroll
            for (int u = 0; u < 4; ++u)
                v[u] = *(const half8_t*)&xw[(size_t)p[u].x * 40 + c * 8];
            #pragma unroll
            for (int u = 0; u < 4; ++u) {
                float w = __int_as_float(p[u].y);
                #pragma unroll
                for (int j = 0; j < 8; ++j) acc[j] += (float)v[u][j] * w;
            }
        }
        for (; e < e1; ++e) {
            int2 p = nt_load_i2(&csr[e]);
            float w = __int_as_float(p.y);
            half8_t v = *(const half8_t*)&xw[(size_t)p.x * 40 + c * 8];
            #pragma unroll
            for (int j = 0; j < 8; ++j) acc[j] += (float)v[j] * w;
        }
        if (active) {
            #pragma unroll
            for (int j = 0; j < 8; ++j) acc[j] += bias[c * 8 + j];
            *(float4*)&out[(size_t)node * 40 + c * 8] =
                make_float4(acc[0], acc[1], acc[2], acc[3]);
            *(float4*)&out[(size_t)node * 40 + c * 8 + 4] =
                make_float4(acc[4], acc[5], acc[6], acc[7]);
        }
    }
}

// ---------------- gemm1: fp16 MFMA, LDS-staged (BK=32, LDK=40 — R27 best) --------
__global__ __launch_bounds__(256) void gemm1_mfma(
        const _Float16* __restrict__ A16, const _Float16* __restrict__ B16,
        const float* __restrict__ bias, _Float16* __restrict__ C16, int M) {
    constexpr int K = 128, N = 256, LDK = 40;
    __shared__ _Float16 sA[128 * LDK];
    __shared__ _Float16 sB[128 * LDK];
    const int t = threadIdx.x;
    const int m0 = blockIdx.x * 128, n0 = blockIdx.y * 128;
    const int wave = t >> 6, lane = t & 63;
    const int wm = wave >> 1, wn = wave & 1;
    const int l15 = lane & 15, k8 = (lane >> 4) * 8;

    f32x4_t acc[4][4] = {};

    for (int k0 = 0; k0 < K; k0 += 32) {
        #pragma unroll
        for (int u = 0; u < 2; ++u) {
            int idx = t + u * 256;
            int r = idx >> 2, c = (idx & 3) * 8;
            int gr = m0 + r; if (gr > M - 1) gr = M - 1;
            *(uint4*)&sA[r * LDK + c] = *(const uint4*)&A16[(size_t)gr * K + k0 + c];
            int bn = n0 + r;
            *(uint4*)&sB[r * LDK + c] = *(const uint4*)&B16[(size_t)bn * K + k0 + c];
        }
        __syncthreads();
        half8_t fa[4], fb[4];
        #pragma unroll
        for (int i = 0; i < 4; ++i) {
            int m = wm * 64 + i * 16 + l15;
            fa[i] = *(const half8_t*)&sA[m * LDK + k8];
            int nn = wn * 64 + i * 16 + l15;
            fb[i] = *(const half8_t*)&sB[nn * LDK + k8];
        }
        #pragma unroll
        for (int i = 0; i < 4; ++i)
            #pragma unroll
            for (int j = 0; j < 4; ++j)
                acc[i][j] = __builtin_amdgcn_mfma_f32_16x16x32_f16(fa[i], fb[j], acc[i][j], 0, 0, 0);
        __syncthreads();
    }

    const int r4 = (lane >> 4) * 4;
    #pragma unroll
    for (int j = 0; j < 4; ++j) {
        int col = n0 + wn * 64 + j * 16 + l15;
        float bv = bias[col];
        #pragma unroll
        for (int i = 0; i < 4; ++i) {
            #pragma unroll
            for (int r = 0; r < 4; ++r) {
                int row = m0 + wm * 64 + i * 16 + r4 + r;
                if (row < M) {
                    float v = fmaxf(acc[i][j][r] + bv, 0.f);
                    C16[(size_t)row * N + col] = (_Float16)v;
                }
            }
        }
    }
}

// ---------------- gemm2: fp16 MFMA, LDS-staged; fp16 output ----------------
__global__ __launch_bounds__(256) void gemm2_mfma(
        const _Float16* __restrict__ A16, const _Float16* __restrict__ B16,
        _Float16* __restrict__ C16, int M) {
    constexpr int K = 256, LDK = 40;
    __shared__ _Float16 sA[128 * LDK];
    __shared__ _Float16 sB[48 * LDK];
    const int t = threadIdx.x;
    const int m0 = blockIdx.x * 128;
    const int wave = t >> 6, lane = t & 63;
    const int l15 = lane & 15, k8 = (lane >> 4) * 8;

    f32x4_t acc[2][3] = {};

    for (int k0 = 0; k0 < K; k0 += 32) {
        #pragma unroll
        for (int u = 0; u < 2; ++u) {
            int idx = t + u * 256;
            int r = idx >> 2, c = (idx & 3) * 8;
            int gr = m0 + r; if (gr > M - 1) gr = M - 1;
            *(uint4*)&sA[r * LDK + c] = *(const uint4*)&A16[(size_t)gr * K + k0 + c];
        }
        if (t < 192) {
            int r = t >> 2, c = (t & 3) * 8;
            *(uint4*)&sB[r * LDK + c] = *(const uint4*)&B16[(size_t)r * K + k0 + c];
        }
        __syncthreads();
        half8_t fa[2], fb[3];
        #pragma unroll
        for (int i = 0; i < 2; ++i) {
            int m = wave * 32 + i * 16 + l15;
            fa[i] = *(const half8_t*)&sA[m * LDK + k8];
        }
        #pragma unroll
        for (int j = 0; j < 3; ++j) {
            int nn = j * 16 + l15;
            fb[j] = *(const half8_t*)&sB[nn * LDK + k8];
        }
        #pragma unroll
        for (int i = 0; i < 2; ++i)
            #pragma unroll
            for (int j = 0; j < 3; ++j)
                acc[i][j] = __builtin_amdgcn_mfma_f32_16x16x32_f16(fa[i], fb[j], acc[i][j], 0, 0, 0);
        __syncthreads();
    }

    const int r4 = (lane >> 4) * 4;
    #pragma unroll
    for (int i = 0; i < 2; ++i)
        #pragma unroll
        for (int j = 0; j < 3; ++j) {
            int col = j * 16 + l15;
            if (col < 40) {
                #pragma unroll
                for (int r = 0; r < 4; ++r) {
                    int row = m0 + wave * 32 + i * 16 + r4 + r;
                    if (row < M) C16[(size_t)row * 40 + col] = (_Float16)acc[i][j][r];
                }
            }
        }
}

extern "C" void kernel_launch(void* const* d_in, const int* in_sizes, int n_in,
                              void* d_out, int out_size, void* d_ws, size_t ws_size,
                              hipStream_t stream) {
    const float* x   = (const float*)d_in[0];
    const int*   ei  = (const int*)d_in[1];
    const float* W1  = (const float*)d_in[2];
    const float* b1  = (const float*)d_in[3];
    const float* W2  = (const float*)d_in[4];
    const float* b2  = (const float*)d_in[5];
    const float* Wfc = (const float*)d_in[6];
    const float* bfc = (const float*)d_in[7];
    float* out = (float*)d_out;

    const int n = N_NODES, E = N_EDGES;
    const int* src = ei;
    const int* dst = ei + E;

    char* ws = (char*)d_ws;
    int*       deg    = (int*)(ws + 0);            // 400 KB
    float*     dinv   = (float*)(ws + 409600);     // 400 KB
    int*       rowptr = (int*)(ws + 819200);       // ~400 KB
    int*       bsums  = (int*)(ws + 1219584);      // 512 B
    float*     bfc2   = (float*)(ws + 1220096);    // 512 B
    _Float16*  w2t16  = (_Float16*)(ws + 1220608); // 24 KB [48][256]
    _Float16*  w1t16  = (_Float16*)(ws + 1245184); // 64 KB [256][128]
    int*       gcur   = (int*)(ws + 1310720);      // 512 B
    int*       cur    = (int*)(ws + 1311232);      // 401,408 B (98*1024 ints)
    int2*      csr    = (int2*)(ws + 1712640);     // 12.8 MB
    int2*      tmp    = (int2*)(ws + 14512640);    // 14.45 MB (capacity-padded bins)
    _Float16*  x16    = (_Float16*)(ws + 28963328);  // 25.6 MB
    _Float16*  aggx16 = (_Float16*)(ws + 54563328);  // 25.6 MB
    _Float16*  h116   = (_Float16*)(ws + 80163328);  // 51.2 MB
    _Float16*  h1w16  = (_Float16*)(ws + 131363328); // 8 MB ([100k][40] fp16)

    const int nb = (n + 1023) / 1024;             // 98 scan blocks
    const int nchunk = (E + CHUNK - 1) / CHUNK;   // 391 binning blocks

    // ---- CSR build: self-reserving binning -> sub-block deg/place ----
    gcur_init_kernel<<<1, 128, 0, stream>>>(gcur);
    hipMemsetAsync(deg, 0, (size_t)n * sizeof(int), stream);
    hipMemsetAsync(cur, 0, (size_t)NBIN * 1024 * sizeof(int), stream);
    binning_kernel<<<nchunk, 256, 0, stream>>>(src, dst, gcur, tmp, E);
    bdeg_kernel<<<NBIN * 4, 1024, 0, stream>>>(gcur, tmp, deg, n);
    scan_sums_kernel<<<nb, 256, 0, stream>>>(deg, bsums, dinv, n);
    scan_offsets_kernel<<<1, 128, 0, stream>>>(bsums, nb, rowptr + n);
    scan_final_kernel<<<nb, 256, 0, stream>>>(deg, bsums, rowptr, n);
    place_kernel<<<NBIN * 4, 1024, 0, stream>>>(gcur, tmp, rowptr, cur, dinv, csr, n);

    // ---- weight precomputes + x fp16 plane ----
    w2fc_kernel<<<1, 256, 0, stream>>>(W2, Wfc, b2, bfc, w2t16, bfc2);
    w1t_kernel<<<128, 256, 0, stream>>>(W1, w1t16);
    x16_kernel<<<(n * 128 / 4 + 255) / 256, 256, 0, stream>>>(x, x16, n * 32);

    // ---- layer 1: aggx(fp16) = A_hat @ x16; h1(fp16) = relu(aggx @ W1 + b1) ----
    gather1_kernel<<<2048, 256, 0, stream>>>(rowptr, csr, dinv, x16, aggx16, n);
    gemm1_mfma<<<dim3((n + 127) / 128, 2), 256, 0, stream>>>(
        aggx16, w1t16, b1, h116, n);

    // ---- layer 2 + FC folded: out = A_hat @ (h1 @ W2fc) + bfc2 ----
    gemm2_mfma<<<(n + 127) / 128, 256, 0, stream>>>(h116, w2t16, h1w16, n);
    gather2_kernel<<<2048, 256, 0, stream>>>(rowptr, csr, dinv, h1w16, bfc2, out, n);
}